// Round 1
// baseline (76.226 us; speedup 1.0000x reference)
//
#include <hip/hip_runtime.h>

#define D8      8
#define LPATH   2048
#define NBATCH  64
#define NSTEPS  2047         // L-1 increments
#define NCHUNK  32
#define CSTEPS  64           // increments per chunk (last chunk: 63)
#define SIGLEN  4680         // 8 + 64 + 512 + 4096
#define OFF2    8
#define OFF3    72
#define OFF4    584

__device__ __forceinline__ void load8(const float* __restrict__ p, float* v) {
    float4 a = ((const float4*)p)[0];
    float4 b = ((const float4*)p)[1];
    v[0]=a.x; v[1]=a.y; v[2]=a.z; v[3]=a.w;
    v[4]=b.x; v[5]=b.y; v[6]=b.z; v[7]=b.w;
}
__device__ __forceinline__ void store8(float* __restrict__ p, const float* v) {
    ((float4*)p)[0] = make_float4(v[0],v[1],v[2],v[3]);
    ((float4*)p)[1] = make_float4(v[4],v[5],v[6],v[7]);
}

// Phase 1: one wave per (batch, chunk). Lane t=(i,j) owns A2[i,j], A3[i,j][8], A4[i,j][8][8].
__global__ __launch_bounds__(64) void sig_chunk_kernel(const float* __restrict__ path,
                                                       float* __restrict__ sigs) {
    const int wg   = blockIdx.x;          // b*NCHUNK + g
    const int b    = wg >> 5;
    const int g    = wg & (NCHUNK - 1);
    const int t0   = g * CSTEPS;
    const int t1   = (t0 + CSTEPS < NSTEPS) ? (t0 + CSTEPS) : NSTEPS;
    const int lane = threadIdx.x;
    const int i    = lane >> 3;
    const int j    = lane & 7;
    const float* __restrict__ pb = path + (size_t)b * LPATH * D8;

    float A4[8][8], A3[8];
    float A2 = 0.f, a1i = 0.f;
#pragma unroll
    for (int k = 0; k < 8; ++k) {
        A3[k] = 0.f;
#pragma unroll
        for (int l = 0; l < 8; ++l) A4[k][l] = 0.f;
    }

    // point buffers: pc = p[t], pn = p[t+1]; per-lane scalars p[.][i], p[.][j]
    float pc[8], pn[8];
    load8(pb + (size_t)t0 * D8, pc);
    load8(pb + (size_t)(t0 + 1) * D8, pn);
    float pci = pb[t0 * D8 + i],       pcj = pb[t0 * D8 + j];
    float pni = pb[(t0 + 1) * D8 + i], pnj = pb[(t0 + 1) * D8 + j];

    for (int t = t0; t < t1; ++t) {
        // prefetch p[t+2] (clamped; hidden under the FMAs below)
        const int tp = (t + 2 < LPATH) ? (t + 2) : (LPATH - 1);
        float pf[8];
        load8(pb + (size_t)tp * D8, pf);
        float pfi = pb[tp * D8 + i], pfj = pb[tp * D8 + j];

        float z[8];
#pragma unroll
        for (int m = 0; m < 8; ++m) z[m] = pn[m] - pc[m];
        const float zi = pni - pci;
        const float zj = pnj - pcj;

        const float p  = zi * zj;
        const float uq = a1i * zj;
        const float c4 = fmaf(uq, 1.f/6.f, fmaf(p, 1.f/24.f, A2 * 0.5f));
        const float c3 = fmaf(uq, 0.5f,    fmaf(p, 1.f/6.f,  A2));

        float f[8];
#pragma unroll
        for (int k = 0; k < 8; ++k) f[k] = fmaf(c4, z[k], A3[k]);
#pragma unroll
        for (int k = 0; k < 8; ++k)
#pragma unroll
            for (int l = 0; l < 8; ++l) A4[k][l] = fmaf(f[k], z[l], A4[k][l]);
#pragma unroll
        for (int k = 0; k < 8; ++k) A3[k] = fmaf(c3, z[k], A3[k]);
        A2 = A2 + fmaf(p, 0.5f, uq);
        a1i += zi;

#pragma unroll
        for (int m = 0; m < 8; ++m) { pc[m] = pn[m]; pn[m] = pf[m]; }
        pci = pni; pcj = pnj; pni = pfi; pnj = pfj;
    }

    float* __restrict__ o = sigs + (size_t)wg * SIGLEN;
    if (lane < 8) o[lane] = pb[(size_t)t1 * D8 + lane] - pb[(size_t)t0 * D8 + lane]; // A1 telescopes
    o[OFF2 + lane] = A2;
    store8(o + OFF3 + lane * 8, A3);
#pragma unroll
    for (int k = 0; k < 8; ++k) store8(o + OFF4 + lane * 64 + k * 8, A4[k]);
}

// Phase 2: general Chen combine C_k = A_k + B_k + sum_{j<k} A_{k-j} (x) B_j.
// One wave per group; A held in registers, B streamed from global (broadcast-friendly).
__global__ __launch_bounds__(64) void sig_combine_kernel(const float* __restrict__ in,
                                                         float* __restrict__ out,
                                                         int nper) {
    const int grp  = blockIdx.x;
    const int lane = threadIdx.x;
    const int i    = lane >> 3;
    const int j    = lane & 7;
    const float* __restrict__ base = in + (size_t)grp * nper * SIGLEN;

    float A4[8][8], A3[8], A1[8], A2, a1i;
    load8(base, A1);
    a1i = base[i];
    A2  = base[OFF2 + lane];
    load8(base + OFF3 + lane * 8, A3);
#pragma unroll
    for (int k = 0; k < 8; ++k) load8(base + OFF4 + lane * 64 + k * 8, A4[k]);

    for (int s = 1; s < nper; ++s) {
        const float* __restrict__ B = base + (size_t)s * SIGLEN;
        float B1[8];  load8(B, B1);
        const float b1i = B[i];
        const float b1j = B[j];
        const float b2t = B[OFF2 + lane];
        float b3ij[8]; load8(B + OFF3 + lane * 8, b3ij);      // B3[i,j,:]
        float b2j[8];  load8(B + OFF2 + j * 8, b2j);          // B2[j,:]

        // C4[i,j,k,l] = A4 + B4 + A3[i,j,k]*B1[l] + A2[i,j]*B2[k,l] + A1[i]*B3[j,k,l]
#pragma unroll
        for (int k = 0; k < 8; ++k) {
            float b4r[8]; load8(B + OFF4 + lane * 64 + k * 8, b4r);
            float b2r[8]; load8(B + OFF2 + k * 8, b2r);       // broadcast
            float b3r[8]; load8(B + OFF3 + j * 64 + k * 8, b3r);
#pragma unroll
            for (int l = 0; l < 8; ++l) {
                float v = A4[k][l] + b4r[l];
                v = fmaf(A3[k], B1[l], v);
                v = fmaf(A2,    b2r[l], v);
                A4[k][l] = fmaf(a1i, b3r[l], v);
            }
        }
        // C3[i,j,k] = A3 + B3[i,j,k] + A2*B1[k] + A1[i]*B2[j,k]
#pragma unroll
        for (int k = 0; k < 8; ++k) {
            float v = A3[k] + b3ij[k];
            v = fmaf(A2, B1[k], v);
            A3[k] = fmaf(a1i, b2j[k], v);
        }
        // C2[i,j] = A2 + B2[i,j] + A1[i]*B1[j]
        A2 = A2 + fmaf(a1i, b1j, b2t);
        // C1 = A1 + B1
#pragma unroll
        for (int m = 0; m < 8; ++m) A1[m] += B1[m];
        a1i += b1i;
    }

    float* __restrict__ o = out + (size_t)grp * SIGLEN;
    if (lane < 8) o[lane] = A1[lane];
    o[OFF2 + lane] = A2;
    store8(o + OFF3 + lane * 8, A3);
#pragma unroll
    for (int k = 0; k < 8; ++k) store8(o + OFF4 + lane * 64 + k * 8, A4[k]);
}

extern "C" void kernel_launch(void* const* d_in, const int* in_sizes, int n_in,
                              void* d_out, int out_size, void* d_ws, size_t ws_size,
                              hipStream_t stream) {
    const float* path = (const float*)d_in[0];
    float* out   = (float*)d_out;
    float* sigs  = (float*)d_ws;                                  // 64*32*4680 f32
    float* gsigs = sigs + (size_t)NBATCH * NCHUNK * SIGLEN;       // 64*4*4680 f32

    sig_chunk_kernel<<<NBATCH * NCHUNK, 64, 0, stream>>>(path, sigs);
    sig_combine_kernel<<<NBATCH * 4, 64, 0, stream>>>(sigs, gsigs, 8);   // 8 chunks -> 1 group sig
    sig_combine_kernel<<<NBATCH, 64, 0, stream>>>(gsigs, out, 4);        // 4 groups -> final
}